// Round 9
// baseline (140.385 us; speedup 1.0000x reference)
//
#include <hip/hip_runtime.h>
#include <hip/hip_bf16.h>
#include <stdint.h>

// Problem constants (B=8192, D=256 fixed by reference setup_inputs)
#define NB 8192          // batch rows
#define ND 256           // feature dim (= full K)
#define NW 16384         // rows of W = [v; u]
#define BM 128           // rows per block
#define BN 64            // cols per panel
#define NSTRIP 4         // column strips
#define STRIPW 4096      // cols per strip
#define NPANEL (STRIPW / BN)   // 64 panels per block
// rows pre-scaled by rw*sqrt(log2e/T): dot == (sim/T)*log2e, so
// exp(sim/T) == exp2(dot) -> one raw v_exp_f32, no multiply, no guards.
#define SQRT_SCALE 4.53981596f  // sqrt(log2(e)/0.07)
#define LN2F 0.69314718f

typedef __bf16 bf16x8 __attribute__((ext_vector_type(8)));
typedef float floatx4 __attribute__((ext_vector_type(4)));

__device__ __forceinline__ void gload_lds16(const void* g, void* l) {
    __builtin_amdgcn_global_load_lds(
        (const __attribute__((address_space(1))) unsigned int*)g,
        (__attribute__((address_space(3))) unsigned int*)l,
        16, 0, 0);
}

// raw v_exp_f32 (r7: exp2f() is an OCML call ~14cyc; inputs bounded ~|25|)
__device__ __forceinline__ float fexp2(float x) {
    return __builtin_amdgcn_exp2f(x);
}

// ---------------------------------------------------------------------------
// Kernel 1: W[row] = concat(v,u)[row] * (1/||row||) * sqrt(log2e/T), bf16.
// ---------------------------------------------------------------------------
__global__ __launch_bounds__(512) void prep_kernel(
    const float* __restrict__ u, const float* __restrict__ v,
    __hip_bfloat16* __restrict__ W, float* __restrict__ out)
{
    const int t    = threadIdx.x;
    if (blockIdx.x == 0 && t == 0) out[0] = 0.f;
    const int row  = blockIdx.x * 8 + (t >> 6);       // 0..16383
    const int lane = t & 63;
    const float* src = (row < NB) ? (v + (size_t)row * ND)
                                  : (u + (size_t)(row - NB) * ND);
    float4 x = ((const float4*)src)[lane];
    float ss = x.x * x.x + x.y * x.y + x.z * x.z + x.w * x.w;
#pragma unroll
    for (int off = 1; off < 64; off <<= 1) ss += __shfl_xor(ss, off, 64);
    const float sc = rsqrtf(ss) * SQRT_SCALE;
    ushort4 o;
    __hip_bfloat16 h;
    h = __float2bfloat16(x.x * sc); o.x = *(const unsigned short*)&h;
    h = __float2bfloat16(x.y * sc); o.y = *(const unsigned short*)&h;
    h = __float2bfloat16(x.z * sc); o.z = *(const unsigned short*)&h;
    h = __float2bfloat16(x.w * sc); o.w = *(const unsigned short*)&h;
    ((ushort4*)(W + (size_t)row * ND))[lane] = o;
}

// ---------------------------------------------------------------------------
// Kernel 2: fused GEMM+exp+rowsum -- register-true repartition + SGB interleave.
// Round-8 discovery: the old af[4][8] = 128 VGPRs NEVER fit in registers;
// the compiler rematerialized A-fragment loads inside every panel (invisible
// in FETCH_SIZE -- L2 traffic), a serial tax in every prior schedule. Also,
// waves issue IN ORDER: an MFMA cluster followed by an exp cluster cannot
// overlap within a wave. Both fixed:
//  - Wave owns 16 rows x ALL 64 panel cols: af[8] = 32 VGPRs (fits),
//    rsum[4] (was 16), col-sums wave-local (no end LDS reduction).
//  - Ping-pong accA/accB (+16 regs; total ~110): panel t's MFMAs and panel
//    t-1's exps live in ONE basic block (branchless epi), interleaved by
//    sched_group_barrier {DS_READ 4 | MFMA 4 | VALU 8} x8 (T19 pattern).
//  - Diagonal: add-then-subtract fixup in a rare wave-uniform branch after
//    the region (error <= 1 ulp of one partial sum); pos kept in a register.
//  - r8 skeleton kept: block-shared 32KB panels, ring-4 (128KB LDS),
//    vmcnt(8) counted waits, raw s_barrier, stage t+3 after the barrier.
// Swizzle (0 conflicts r1..r8): 16B chunk c of row r at c^(r&15).
// XCD map: s=(b>>1)&3, rt=((b>>3)<<1)|(b&1).
// ---------------------------------------------------------------------------
__global__ __launch_bounds__(512, 2) void dcl_main(
    const __hip_bfloat16* __restrict__ W,   // 16384 x 256, pre-scaled
    float* __restrict__ partial,            // [4][8192] slot = strip
    float* __restrict__ pos)                // 8192
{
    const int b  = blockIdx.x;
    const int s  = (b >> 1) & 3;                    // strip; XCD(b)=b%8 in {2s,2s+1}
    const int rt = ((b >> 3) << 1) | (b & 1);       // row tile 0..63
    const int rb = rt * BM;

    const __hip_bfloat16* A = W + (size_t)NB * ND;  // u rows

    __shared__ __align__(16) char lds[131072];      // ring-4 x 32 KB panels

    const int tid  = threadIdx.x;
    const int wave = tid >> 6;              // 0..7 : 16-row group of A
    const int lane = tid & 63;
    const int quad = lane >> 4;             // 0..3
    const int tcol = lane & 15;             // 0..15
    const int rh   = lane >> 5;             // stage: row half within 1KB chunk
    const int cl   = lane & 31;             // stage: 16B chunk index (0..31)

    const int sbase = s * STRIPW;

#define WAITV(N) do {                                                        \
    asm volatile("s_waitcnt vmcnt(" #N ")" ::: "memory");                    \
    __builtin_amdgcn_sched_barrier(0);                                       \
} while (0)

// Stage panel T (32 KB) block-shared: wave stages local rows [wave*8,+8).
#define STAGE(T) do {                                                        \
    char* dst_ = lds + ((T) & 3) * 32768 + wave * 4096;                      \
    const int cb_ = sbase + (T) * BN;                                        \
    _Pragma("unroll")                                                        \
    for (int i_ = 0; i_ < 4; i_++) {                                         \
        int rl_ = wave * 8 + i_ * 2 + rh;        /* local row 0..63 */       \
        gload_lds16(W + (size_t)(cb_ + rl_) * ND + ((cl ^ (rl_ & 15)) << 3), \
                    dst_ + i_ * 1024);                                       \
    }                                                                        \
} while (0)

// Compute panel T into ACCC; branchless epilogue of prev panel from ACCP.
// One basic block; SGB pins {DS 4 | MFMA 4 | VALU 8} interleave.
#define COMPUTE_EPI(T, ACCC, ACCP) do {                                      \
    const char* sb_ = lds + ((T) & 3) * 32768;                               \
    _Pragma("unroll")                                                        \
    for (int nt_ = 0; nt_ < 4; nt_++) ACCC[nt_] = (floatx4){0.f,0.f,0.f,0.f};\
    _Pragma("unroll")                                                        \
    for (int ks_ = 0; ks_ < 8; ks_++) {                                      \
        _Pragma("unroll")                                                    \
        for (int nt_ = 0; nt_ < 4; nt_++) {                                  \
            bf16x8 bb_ = *(const bf16x8*)(sb_ + (nt_ * 16 + tcol) * 512 +    \
                                          ((((ks_ * 4) + quad) ^ tcol) << 4));\
            ACCC[nt_] = __builtin_amdgcn_mfma_f32_16x16x32_bf16(             \
                af[ks_], bb_, ACCC[nt_], 0, 0, 0);                           \
        }                                                                    \
    }                                                                        \
    _Pragma("unroll")                                                        \
    for (int nt_ = 0; nt_ < 4; nt_++)                                        \
        _Pragma("unroll")                                                    \
        for (int rg_ = 0; rg_ < 4; rg_++)                                    \
            rsum[rg_] += fexp2(ACCP[nt_][rg_]);                              \
    __builtin_amdgcn_sched_group_barrier(0x100, 4, 0);  /* DS_READ x4 */     \
    _Pragma("unroll")                                                        \
    for (int g_ = 0; g_ < 8; g_++) {                                         \
        __builtin_amdgcn_sched_group_barrier(0x008, 4, 0);  /* MFMA x4 */    \
        __builtin_amdgcn_sched_group_barrier(0x002, 8, 0);  /* VALU x8 */    \
        if (g_ < 7) __builtin_amdgcn_sched_group_barrier(0x100, 4, 0);       \
    }                                                                        \
} while (0)

// Rare diagonal fixup for panel T (acc ACCP): subtract the exp the
// branchless epi added for the diagonal element; capture pos in a register.
#define FIXUP(ACCP, T) do {                                                  \
    if (sbase + (T) * BN == dpp) {                                           \
        _Pragma("unroll")                                                    \
        for (int nt_ = 0; nt_ < 4; nt_++)                                    \
            _Pragma("unroll")                                                \
            for (int rg_ = 0; rg_ < 4; rg_++) {                              \
                bool sel_ = (nt_ == dnt) && (tcol == quad * 4 + rg_);        \
                float sc_ = ACCP[nt_][rg_];                                  \
                if (sel_) { posv = sc_; rsum[rg_] -= fexp2(sc_); }           \
            }                                                                \
    }                                                                        \
} while (0)

#define PHASE(T, ACCC, ACCP, NWAIT, DOSTAGE) do {                            \
    WAITV(NWAIT);                                                            \
    __builtin_amdgcn_s_barrier();                                            \
    if (DOSTAGE) STAGE((T) + 3);                                             \
    __builtin_amdgcn_sched_barrier(0);                                       \
    __builtin_amdgcn_s_setprio(1);                                           \
    COMPUTE_EPI(T, ACCC, ACCP);                                              \
    __builtin_amdgcn_s_setprio(0);                                           \
    FIXUP(ACCP, (T) - 1);                                                    \
} while (0)

    // ---- A fragments: global -> registers (32 VGPRs), issued FIRST ----
    // 16x16x32 A-frag (m89-verified): lane(quad,tcol) = row tcol(+base),
    // k in [ks*32 + quad*8, +8)
    bf16x8 af[8];
    {
        const __hip_bfloat16* ar =
            A + (size_t)(rb + wave * 16 + tcol) * ND + quad * 8;
#pragma unroll
        for (int ks = 0; ks < 8; ks++)
            af[ks] = *(const bf16x8*)(ar + ks * 32);
    }

    // prologue: panels 0..2 in flight (12 loads/wave)
    STAGE(0); STAGE(1); STAGE(2);

    // diag block (wave-uniform): 16 cols [dp, dp+16) inside panel dpp
    const bool isuv = (s < 2);
    const int  dp = rb + wave * 16 + (isuv ? 0 : NB);
    const bool dvalid = ((dp >> 12) == s);
    const int  dpp = dvalid ? (dp & ~63) : 0x40000000;  // sentinel if not ours
    const int  dnt = (dp >> 4) & 3;

    float rsum[4] = {0.f, 0.f, 0.f, 0.f};
    float posv = 0.f;
    floatx4 accA[4], accB[4];
#pragma unroll
    for (int nt = 0; nt < 4; nt++)
        accB[nt] = (floatx4){-1e38f, -1e38f, -1e38f, -1e38f};  // exp2 -> 0

#pragma unroll 1
    for (int t = 0; t < NPANEL - 4; t += 2) {   // t = 0..58
        PHASE(t,     accA, accB, 8, 1);
        PHASE(t + 1, accB, accA, 8, 1);
    }
    PHASE(60, accA, accB, 8, 1);   // stages panel 63
    PHASE(61, accB, accA, 8, 0);
    PHASE(62, accA, accB, 4, 0);
    PHASE(63, accB, accA, 0, 0);
    // final epilogue: panel 63 (accB)
#pragma unroll
    for (int nt = 0; nt < 4; nt++)
#pragma unroll
        for (int rg = 0; rg < 4; rg++)
            rsum[rg] += fexp2(accB[nt][rg]);
    FIXUP(accB, 63);

#undef WAITV
#undef STAGE
#undef COMPUTE_EPI
#undef FIXUP
#undef PHASE

    // diagonal pos store (uv only): holder lanes have quad == tcol>>2;
    // convert log2-units back: sim/T = dot * ln2
    if (isuv && dvalid && (tcol >> 2) == quad)
        pos[rb + wave * 16 + quad * 4 + (tcol & 3)] = posv * LN2F;

    // row sums are wave-complete over cols: reduce across the 16 tcol lanes
#pragma unroll
    for (int rg = 0; rg < 4; rg++) {
        float v = rsum[rg];
        v += __shfl_xor(v, 1, 16);
        v += __shfl_xor(v, 2, 16);
        v += __shfl_xor(v, 4, 16);
        v += __shfl_xor(v, 8, 16);
        if (tcol == 0)
            partial[(size_t)s * NB + rb + wave * 16 + quad * 4 + rg] = v;
    }
}

// ---------------------------------------------------------------------------
// Kernel 3: loss = mean_i( log(sum_strips partial[s][i]) - pos_i )
// ---------------------------------------------------------------------------
__global__ __launch_bounds__(256) void finalize_kernel(
    const float* __restrict__ partial, const float* __restrict__ pos,
    float* __restrict__ out)
{
    const int i = blockIdx.x * 256 + threadIdx.x;   // 0..8191
    float tot = partial[i] + partial[NB + i] + partial[2 * NB + i]
              + partial[3 * NB + i];
    float sv = logf(tot) - pos[i];
#pragma unroll
    for (int off = 32; off > 0; off >>= 1) sv += __shfl_down(sv, off, 64);
    __shared__ float wsum[4];
    const int t = threadIdx.x;
    if ((t & 63) == 0) wsum[t >> 6] = sv;
    __syncthreads();
    if (t == 0) {
        float blk = (wsum[0] + wsum[1]) + (wsum[2] + wsum[3]);
        atomicAdd(out, blk / (float)NB);
    }
}

extern "C" void kernel_launch(void* const* d_in, const int* in_sizes, int n_in,
                              void* d_out, int out_size, void* d_ws, size_t ws_size,
                              hipStream_t stream) {
    const float* u = (const float*)d_in[0];
    const float* v = (const float*)d_in[1];
    float* out = (float*)d_out;

    char* ws = (char*)d_ws;
    __hip_bfloat16* W = (__hip_bfloat16*)ws;                      // 8 MB
    float* partial = (float*)(ws + (size_t)NW * ND * sizeof(__hip_bfloat16));
    float* pos     = partial + NSTRIP * NB;                       // 8192 floats

    prep_kernel<<<NW / 8, 512, 0, stream>>>(u, v, W, out);
    dcl_main<<<256, 512, 0, stream>>>(W, partial, pos);
    finalize_kernel<<<NB / 256, 256, 0, stream>>>(partial, pos, out);
}